// Round 1
// baseline (257.209 us; speedup 1.0000x reference)
//
#include <hip/hip_runtime.h>

// Izhikevich spiking neuron scan.
// x: [T=512, N=65536] f32. out: [T, N] f32 spike train (0.0 / 1.0).
// Per neuron (independent chains):
//   v0 = -0.065, r0 = 0
//   v  = (4v^2 + 5v + 1.4 - r + x_t) * DT      (DT = 1/512)
//   r  = 0.02 * (0.2v - v) * DT                (uses NEW v)
//   fire = v >= 0.3 ; v = fire ? -0.065 : v ; r = fire ? r+0.008 : r
//   out_t = fire ? 1.0 : 0.0

#define T_STEPS 512
#define N_NEUR  65536
#define DT      (1.0f / 512.0f)

__global__ __launch_bounds__(256) void izi_kernel(const float* __restrict__ x,
                                                  float* __restrict__ out) {
    const int n = blockIdx.x * 256 + threadIdx.x;   // 0..65535, coalesced per wave
    const float* xp = x + n;
    float*       op = out + n;

    float v = -0.065f;
    float r = 0.0f;

    // Addresses are independent of the recurrence state, so with __restrict__
    // and unrolling the compiler can issue a batch of loads ahead of the
    // dependent ALU chain (latency hiding without LDS).
    #pragma unroll 8
    for (int t = 0; t < T_STEPS; ++t) {
        const float xt = xp[(size_t)t * N_NEUR];
        v = (4.0f * v * v + 5.0f * v + 1.4f - r + xt) * DT;
        r = 0.02f * (0.2f * v - v) * DT;
        const bool fire = v >= 0.3f;
        op[(size_t)t * N_NEUR] = fire ? 1.0f : 0.0f;
        if (fire) { v = -0.065f; r = r + 0.008f; }
    }
}

extern "C" void kernel_launch(void* const* d_in, const int* in_sizes, int n_in,
                              void* d_out, int out_size, void* d_ws, size_t ws_size,
                              hipStream_t stream) {
    const float* x = (const float*)d_in[0];
    float* out = (float*)d_out;
    // 65536 neurons / 256 threads = 256 blocks -> exactly 1 block (4 waves) per CU.
    izi_kernel<<<dim3(N_NEUR / 256), dim3(256), 0, stream>>>(x, out);
}

// Round 2
// 231.238 us; speedup vs baseline: 1.1123x; 1.1123x over previous
//
#include <hip/hip_runtime.h>

// Izhikevich spiking neuron scan, time-chunked for occupancy.
// x: [T=512, N=65536] f32. out: [T, N] f32 spike train (0.0 / 1.0).
//
// Recurrence per neuron:
//   v = (4v^2 + 5v + 1.4 - r + x_t) * DT   (DT = 1/512)
//   r = 0.02 * (0.2v - v) * DT             (uses NEW v)
//   fire = v >= 0.3 ; fire -> v = -0.065, r += 0.008 ; out_t = fire
//
// Time-split justification: the map contracts prior state by ~(5/512) per
// step (|v| <= ~0.02, r ~ 3e-5*v), so 8 warmup steps shrink any init-state
// error by ~1e-16 — below fp32 ulp. The output bit (v >= 0.3, margin ~20x)
// is insensitive regardless. 8 chunks x 256 blocks = 2048 blocks ->
// 8 blocks/CU = 32 waves/CU (max occupancy) vs 1 wave/SIMD before.

#define T_STEPS 512
#define N_NEUR  65536
#define DT      (1.0f / 512.0f)
#define TCH     64          // timesteps written per chunk (512/8)
#define WARM    8           // warmup steps to converge state at chunk start

__device__ __forceinline__ void izi_step(float xt, float& v, float& r, bool& fire) {
    v = (4.0f * v * v + 5.0f * v + 1.4f - r + xt) * DT;
    r = 0.02f * (0.2f * v - v) * DT;
    fire = v >= 0.3f;
    if (fire) { v = -0.065f; r += 0.008f; }
}

__global__ __launch_bounds__(256, 8) void izi_kernel(const float* __restrict__ x,
                                                     float* __restrict__ out) {
    const int n = blockIdx.x * 256 + threadIdx.x;   // neuron, coalesced per wave
    const int c = blockIdx.y;                       // time chunk 0..7
    const int tstart = c * TCH;

    float v = -0.065f;   // matches true init at t=0; for c>0 it's the warmup seed
    float r = 0.0f;
    bool fire;

    if (c > 0) {
        #pragma unroll
        for (int t = tstart - WARM; t < tstart; ++t) {
            const float xt = x[(size_t)t * N_NEUR + n];
            izi_step(xt, v, r, fire);
        }
    }

    // Unrolled by 8: addresses are state-independent, so the compiler can
    // issue each batch of 8 loads before the dependent recurrence chain.
    #pragma unroll 8
    for (int t = tstart; t < tstart + TCH; ++t) {
        const float xt = x[(size_t)t * N_NEUR + n];
        izi_step(xt, v, r, fire);
        out[(size_t)t * N_NEUR + n] = fire ? 1.0f : 0.0f;
    }
}

extern "C" void kernel_launch(void* const* d_in, const int* in_sizes, int n_in,
                              void* d_out, int out_size, void* d_ws, size_t ws_size,
                              hipStream_t stream) {
    const float* x = (const float*)d_in[0];
    float* out = (float*)d_out;
    // grid: 256 neuron-blocks x 8 time-chunks = 2048 blocks (8 per CU).
    izi_kernel<<<dim3(N_NEUR / 256, T_STEPS / TCH), dim3(256), 0, stream>>>(x, out);
}